// Round 5
// baseline (755.598 us; speedup 1.0000x reference)
//
#include <hip/hip_runtime.h>

#define N_NODES 100000
#define N_EDGES 1600000
#define SCAN_NB ((N_NODES + 255) / 256)   // 391

// packed degree: bits 63..52 = count, bits 51..0 = sum(w) in 2^-32 fixed point
#define CNT_SHIFT 52
#define WSUM_MASK ((1ULL << 52) - 1)

__device__ inline unsigned short f2bf(float f) {   // round-to-nearest-even
    unsigned int u = __float_as_uint(f);
    u += 0x7FFFu + ((u >> 16) & 1u);
    return (unsigned short)(u >> 16);
}
__device__ inline float bflo(unsigned int u) { return __uint_as_float(u << 16); }
__device__ inline float bfhi(unsigned int u) { return __uint_as_float(u & 0xFFFF0000u); }

// ---------------- CSR build ----------------

__global__ void init_packed_kernel(unsigned long long* __restrict__ packed, int n) {
    int i = blockIdx.x * blockDim.x + threadIdx.x;
    if (i < n) packed[i] = 1ULL << 32;   // self-loop weight 1.0, count 0
}

__global__ void edge_pass1_kernel(const int* __restrict__ dst, const float* __restrict__ w,
                                  unsigned long long* __restrict__ packed,
                                  int* __restrict__ rank, int E) {
    int e = blockIdx.x * blockDim.x + threadIdx.x;
    if (e < E) {
        int d = __builtin_nontemporal_load(&dst[e]);
        float we = __builtin_nontemporal_load(&w[e]);
        unsigned long long inc = (1ULL << CNT_SHIFT)
                               + (unsigned long long)((double)we * 4294967296.0);
        unsigned long long old = atomicAdd(&packed[d], inc);
        __builtin_nontemporal_store((int)(old >> CNT_SHIFT), &rank[e]);
    }
}

// scan1 fused with extract: packed -> cnt, dinv, block sums
__global__ __launch_bounds__(256) void scan1_kernel(const unsigned long long* __restrict__ packed,
                                                    int* __restrict__ cnt, float* __restrict__ dinv,
                                                    int* __restrict__ bsum, int n) {
    __shared__ int s[256];
    int tid = threadIdx.x;
    int i = blockIdx.x * 256 + tid;
    int v = 0;
    if (i < n) {
        unsigned long long pk = packed[i];
        v = (int)(pk >> CNT_SHIFT);
        cnt[i] = v;
        float sum = (float)((double)(pk & WSUM_MASK) * (1.0 / 4294967296.0));
        dinv[i] = rsqrtf(sum);   // sum >= 1 always
    }
    s[tid] = v;
    __syncthreads();
    #pragma unroll
    for (int off = 128; off > 0; off >>= 1) {
        if (tid < off) s[tid] += s[tid + off];
        __syncthreads();
    }
    if (tid == 0) bsum[blockIdx.x] = s[0];
}

__global__ __launch_bounds__(512) void scan2_kernel(int* __restrict__ bsum, int nb) {
    __shared__ int s[512];
    int tid = threadIdx.x;
    int v = (tid < nb) ? bsum[tid] : 0;
    s[tid] = v;
    __syncthreads();
    #pragma unroll
    for (int off = 1; off < 512; off <<= 1) {
        int t = s[tid];
        int u = (tid >= off) ? s[tid - off] : 0;
        __syncthreads();
        s[tid] = t + u;
        __syncthreads();
    }
    if (tid < nb) bsum[tid] = (tid == 0) ? 0 : s[tid - 1];
}

__global__ __launch_bounds__(256) void scan3_kernel(const int* __restrict__ cnt,
                                                    const int* __restrict__ bsum,
                                                    int* __restrict__ rowptr, int n) {
    __shared__ int s[256];
    int tid = threadIdx.x;
    int i = blockIdx.x * 256 + tid;
    int v = (i < n) ? cnt[i] : 0;
    s[tid] = v;
    __syncthreads();
    #pragma unroll
    for (int off = 1; off < 256; off <<= 1) {
        int t = s[tid];
        int u = (tid >= off) ? s[tid - off] : 0;
        __syncthreads();
        s[tid] = t + u;
        __syncthreads();
    }
    if (i < n) rowptr[i] = bsum[blockIdx.x] + s[tid] - v;
    if (i == 0) rowptr[n] = N_EDGES;
}

// interleaved edge record: low dword = src, high dword = norm bits
__global__ void place_kernel(const int* __restrict__ src, const int* __restrict__ dst,
                             const float* __restrict__ w, const float* __restrict__ dinv,
                             const int* __restrict__ rowptr, const int* __restrict__ rank,
                             unsigned long long* __restrict__ edges, int E) {
    int e = blockIdx.x * blockDim.x + threadIdx.x;
    if (e < E) {
        int s = __builtin_nontemporal_load(&src[e]);
        int d = __builtin_nontemporal_load(&dst[e]);
        float we = __builtin_nontemporal_load(&w[e]);
        int rk = __builtin_nontemporal_load(&rank[e]);
        int pos = rowptr[d] + rk;
        float nrm = dinv[s] * we * dinv[d];
        unsigned long long rec = ((unsigned long long)__float_as_uint(nrm) << 32)
                               | (unsigned int)s;
        __builtin_nontemporal_store(rec, &edges[pos]);
    }
}

// ---------------- GEMM: H = X @ W  (f32 compute, bf16 store; X f32 or bf16) ----------------

template<bool XBF16>
__global__ __launch_bounds__(256) void gemm_kernel(const void* __restrict__ Xin,
                                                   const float* __restrict__ W,
                                                   unsigned short* __restrict__ Hout,
                                                   int M, int FOUT, int HSTRIDE) {
    __shared__ float sX[64 * 128];
    __shared__ float sW[128 * 64];
    int row0 = blockIdx.x * 64;
    int col0 = blockIdx.y * 64;
    int tid = threadIdx.x;

    for (int i = tid; i < 128 * 16; i += 256) {
        int k = i >> 4, c4 = i & 15;
        int j = col0 + c4 * 4;
        float4 v = make_float4(0.f, 0.f, 0.f, 0.f);
        if (j + 3 < FOUT) v = *(const float4*)&W[k * FOUT + j];
        ((float4*)sW)[i] = v;
    }
    if (XBF16) {
        const unsigned int* X = (const unsigned int*)Xin;   // 64 dwords per row
        for (int i = tid; i < 64 * 64; i += 256) {
            int r = i >> 6, c2 = i & 63;
            int row = row0 + r;
            unsigned int u = (row < M) ? X[(size_t)row * 64 + c2] : 0u;
            sX[r * 128 + 2 * c2]     = bflo(u);
            sX[r * 128 + 2 * c2 + 1] = bfhi(u);
        }
    } else {
        const float* X = (const float*)Xin;
        for (int i = tid; i < 64 * 32; i += 256) {
            int r = i >> 5;
            int row = row0 + r;
            float4 v = make_float4(0.f, 0.f, 0.f, 0.f);
            if (row < M) v = *(const float4*)&X[(size_t)row * 128 + (i & 31) * 4];
            ((float4*)sX)[i] = v;
        }
    }
    __syncthreads();

    int tx = tid & 15, ty = tid >> 4;
    float acc[4][4] = {};
    const float* xb = &sX[(ty * 4) * 128];
    #pragma unroll 4
    for (int k = 0; k < 128; k++) {
        float4 wv = ((const float4*)sW)[(k << 4) + tx];
        float x0 = xb[k];
        float x1 = xb[128 + k];
        float x2 = xb[256 + k];
        float x3 = xb[384 + k];
        acc[0][0] += x0 * wv.x; acc[0][1] += x0 * wv.y; acc[0][2] += x0 * wv.z; acc[0][3] += x0 * wv.w;
        acc[1][0] += x1 * wv.x; acc[1][1] += x1 * wv.y; acc[1][2] += x1 * wv.z; acc[1][3] += x1 * wv.w;
        acc[2][0] += x2 * wv.x; acc[2][1] += x2 * wv.y; acc[2][2] += x2 * wv.z; acc[2][3] += x2 * wv.w;
        acc[3][0] += x3 * wv.x; acc[3][1] += x3 * wv.y; acc[3][2] += x3 * wv.z; acc[3][3] += x3 * wv.w;
    }

    #pragma unroll
    for (int i2 = 0; i2 < 4; i2++) {
        int row = row0 + ty * 4 + i2;
        if (row < M) {
            int j = col0 + tx * 4;
            if (j + 3 < FOUT) {
                *(ushort4*)&Hout[(size_t)row * HSTRIDE + j] =
                    make_ushort4(f2bf(acc[i2][0]), f2bf(acc[i2][1]),
                                 f2bf(acc[i2][2]), f2bf(acc[i2][3]));
            }
        }
    }
}

// ---------------- Aggregation F=128 (bf16 H, bf16 out): one wave/node ----------------

template<bool RELU>
__global__ __launch_bounds__(256) void gather128bf_kernel(
        const unsigned int* __restrict__ H,                 // N x 64 dwords (bf16x2)
        const int* __restrict__ rowptr,
        const unsigned long long* __restrict__ edges,       // (src, normbits)
        const float* __restrict__ dinv, const float* __restrict__ bias,
        unsigned int* __restrict__ out, int n) {            // N x 64 dwords (bf16x2)
    int wave = threadIdx.x >> 6;
    int lane = threadIdx.x & 63;
    int node = blockIdx.x * 4 + wave;
    if (node >= n) return;
    int beg = rowptr[node], end = rowptr[node + 1];
    float ax = 0.f, ay = 0.f;
    int e = beg;
    for (; e + 7 < end; e += 8) {
        int s[8]; float w[8]; unsigned int u[8];
        #pragma unroll
        for (int i = 0; i < 8; i++) {
            unsigned long long rec = __builtin_nontemporal_load(&edges[e + i]);
            s[i] = (int)(unsigned int)rec;
            w[i] = __uint_as_float((unsigned int)(rec >> 32));
        }
        #pragma unroll
        for (int i = 0; i < 8; i++) { u[i] = H[(size_t)s[i] * 64 + lane]; }
        #pragma unroll
        for (int i = 0; i < 8; i++) {
            ax += w[i] * bflo(u[i]);
            ay += w[i] * bfhi(u[i]);
        }
    }
    for (; e < end; e++) {
        unsigned long long rec = __builtin_nontemporal_load(&edges[e]);
        float w0 = __uint_as_float((unsigned int)(rec >> 32));
        unsigned int u = H[(size_t)(unsigned int)rec * 64 + lane];
        ax += w0 * bflo(u);
        ay += w0 * bfhi(u);
    }
    float di = dinv[node];
    float sw = di * di;
    unsigned int us = H[(size_t)node * 64 + lane];
    ax += sw * bflo(us);
    ay += sw * bfhi(us);
    float2 bv = ((const float2*)bias)[lane];
    ax += bv.x; ay += bv.y;
    if (RELU) { ax = fmaxf(ax, 0.f); ay = fmaxf(ay, 0.f); }
    unsigned int pk = (unsigned int)f2bf(ax) | ((unsigned int)f2bf(ay) << 16);
    __builtin_nontemporal_store(pk, &out[(size_t)node * 64 + lane]);
}

// F=40 (bf16 H padded to 32 dwords/row): one wave/node, lanes 0..19, f32 out ----------------
__global__ __launch_bounds__(256) void gather40bf_kernel(
        const unsigned int* __restrict__ H,   // N x 32 dwords (20 used)
        const int* __restrict__ rowptr,
        const unsigned long long* __restrict__ edges,
        const float* __restrict__ dinv, const float* __restrict__ bias,
        float* __restrict__ out, int n) {
    int wave = threadIdx.x >> 6;
    int lane = threadIdx.x & 63;
    int node = blockIdx.x * 4 + wave;
    if (node >= n || lane >= 20) return;
    int beg = rowptr[node], end = rowptr[node + 1];
    float ax = 0.f, ay = 0.f;
    int e = beg;
    for (; e + 3 < end; e += 4) {
        unsigned long long r0 = __builtin_nontemporal_load(&edges[e]);
        unsigned long long r1 = __builtin_nontemporal_load(&edges[e + 1]);
        unsigned long long r2 = __builtin_nontemporal_load(&edges[e + 2]);
        unsigned long long r3 = __builtin_nontemporal_load(&edges[e + 3]);
        unsigned int u0 = H[(size_t)(unsigned int)r0 * 32 + lane];
        unsigned int u1 = H[(size_t)(unsigned int)r1 * 32 + lane];
        unsigned int u2 = H[(size_t)(unsigned int)r2 * 32 + lane];
        unsigned int u3 = H[(size_t)(unsigned int)r3 * 32 + lane];
        float w0 = __uint_as_float((unsigned int)(r0 >> 32));
        float w1 = __uint_as_float((unsigned int)(r1 >> 32));
        float w2 = __uint_as_float((unsigned int)(r2 >> 32));
        float w3 = __uint_as_float((unsigned int)(r3 >> 32));
        ax += w0 * bflo(u0); ay += w0 * bfhi(u0);
        ax += w1 * bflo(u1); ay += w1 * bfhi(u1);
        ax += w2 * bflo(u2); ay += w2 * bfhi(u2);
        ax += w3 * bflo(u3); ay += w3 * bfhi(u3);
    }
    for (; e < end; e++) {
        unsigned long long rec = __builtin_nontemporal_load(&edges[e]);
        float w0 = __uint_as_float((unsigned int)(rec >> 32));
        unsigned int u = H[(size_t)(unsigned int)rec * 32 + lane];
        ax += w0 * bflo(u); ay += w0 * bfhi(u);
    }
    float di = dinv[node];
    float sw = di * di;
    unsigned int us = H[(size_t)node * 32 + lane];
    ax += sw * bflo(us); ay += sw * bfhi(us);
    float2 bv = ((const float2*)bias)[lane];
    ax += bv.x; ay += bv.y;
    float2 o = make_float2(ax, ay);
    __builtin_nontemporal_store(o.x, &out[(size_t)node * 40 + 2 * lane]);
    __builtin_nontemporal_store(o.y, &out[(size_t)node * 40 + 2 * lane + 1]);
}

// ---------------- launch ----------------

extern "C" void kernel_launch(void* const* d_in, const int* in_sizes, int n_in,
                              void* d_out, int out_size, void* d_ws, size_t ws_size,
                              hipStream_t stream) {
    const float* x  = (const float*)d_in[0];
    const int*   ei = (const int*)d_in[1];
    const float* ew = (const float*)d_in[2];
    const float* W1 = (const float*)d_in[3];
    const float* b1 = (const float*)d_in[4];
    const float* W2 = (const float*)d_in[5];
    const float* b2 = (const float*)d_in[6];
    const float* W3 = (const float*)d_in[7];
    const float* b3 = (const float*)d_in[8];
    float* out = (float*)d_out;

    const int N = N_NODES, E = N_EDGES;
    const int* src = ei;
    const int* dst = ei + E;

    char* p = (char*)d_ws;
    unsigned long long* packed = (unsigned long long*)p; p += 800000;   // N u64
    float* dinv   = (float*)p; p += 400000;
    int*   cnt    = (int*)p;   p += 400000;
    int*   rowptr = (int*)p;   p += 400016;
    int*   bsum   = (int*)p;   p += 2048;
    int*   rank   = (int*)p;   p += 6400000;                            // E i32
    unsigned long long* edges = (unsigned long long*)p; p += 12800000;  // E u64
    void*  A      = (void*)p;  p += (size_t)N * 128 * 2;                // bf16 H
    void*  B      = (void*)p;                                           // bf16 layer output

    int nb = (N + 255) / 256;
    int eb = (E + 255) / 256;

    init_packed_kernel<<<nb, 256, 0, stream>>>(packed, N);
    edge_pass1_kernel<<<eb, 256, 0, stream>>>(dst, ew, packed, rank, E);
    scan1_kernel<<<SCAN_NB, 256, 0, stream>>>(packed, cnt, dinv, bsum, N);
    scan2_kernel<<<1, 512, 0, stream>>>(bsum, SCAN_NB);
    scan3_kernel<<<SCAN_NB, 256, 0, stream>>>(cnt, bsum, rowptr, N);
    place_kernel<<<eb, 256, 0, stream>>>(src, dst, ew, dinv, rowptr, rank, edges, E);

    int rt = (N + 63) / 64;
    dim3 g128(rt, 2);
    dim3 g40(rt, 1);
    int gb = (N + 3) / 4;

    // layer 1: A(bf16) = x(f32)@W1 ; B(bf16) = relu(agg(A)+self+b1)
    gemm_kernel<false><<<g128, 256, 0, stream>>>(x, W1, (unsigned short*)A, N, 128, 128);
    gather128bf_kernel<true><<<gb, 256, 0, stream>>>((const unsigned int*)A, rowptr, edges, dinv, b1, (unsigned int*)B, N);
    // layer 2: bf16 input
    gemm_kernel<true><<<g128, 256, 0, stream>>>(B, W2, (unsigned short*)A, N, 128, 128);
    gather128bf_kernel<true><<<gb, 256, 0, stream>>>((const unsigned int*)A, rowptr, edges, dinv, b2, (unsigned int*)B, N);
    // layer 3: H3 bf16 padded to 64-short rows; f32 output
    gemm_kernel<true><<<g40, 256, 0, stream>>>(B, W3, (unsigned short*)A, N, 40, 64);
    gather40bf_kernel<<<gb, 256, 0, stream>>>((const unsigned int*)A, rowptr, edges, dinv, b3, out, N);
}

// Round 7
// 635.337 us; speedup vs baseline: 1.1893x; 1.1893x over previous
//
#include <hip/hip_runtime.h>

#define N_NODES 100000
#define N_EDGES 1600000
#define SCAN_NB ((N_NODES + 255) / 256)   // 391

// packed degree: bits 63..52 = count, bits 51..0 = sum(w) in 2^-32 fixed point
#define CNT_SHIFT 52
#define WSUM_MASK ((1ULL << 52) - 1)

__device__ inline unsigned short f2bf(float f) {   // round-to-nearest-even
    unsigned int u = __float_as_uint(f);
    u += 0x7FFFu + ((u >> 16) & 1u);
    return (unsigned short)(u >> 16);
}
__device__ inline float bflo(unsigned int u) { return __uint_as_float(u << 16); }
__device__ inline float bfhi(unsigned int u) { return __uint_as_float(u & 0xFFFF0000u); }

// ---------------- CSR build ----------------

__global__ void init_packed_kernel(unsigned long long* __restrict__ packed, int n) {
    int i = blockIdx.x * blockDim.x + threadIdx.x;
    if (i < n) packed[i] = 1ULL << 32;   // self-loop weight 1.0, count 0
}

__global__ void edge_pass1_kernel(const int* __restrict__ dst, const float* __restrict__ w,
                                  unsigned long long* __restrict__ packed,
                                  int* __restrict__ rank, int E) {
    int e = blockIdx.x * blockDim.x + threadIdx.x;
    if (e < E) {
        int d = dst[e];
        unsigned long long inc = (1ULL << CNT_SHIFT)
                               + (unsigned long long)((double)w[e] * 4294967296.0);
        unsigned long long old = atomicAdd(&packed[d], inc);
        rank[e] = (int)(old >> CNT_SHIFT);
    }
}

// scan1 fused with extract: packed -> cnt, dinv, block sums
__global__ __launch_bounds__(256) void scan1_kernel(const unsigned long long* __restrict__ packed,
                                                    int* __restrict__ cnt, float* __restrict__ dinv,
                                                    int* __restrict__ bsum, int n) {
    __shared__ int s[256];
    int tid = threadIdx.x;
    int i = blockIdx.x * 256 + tid;
    int v = 0;
    if (i < n) {
        unsigned long long pk = packed[i];
        v = (int)(pk >> CNT_SHIFT);
        cnt[i] = v;
        float sum = (float)((double)(pk & WSUM_MASK) * (1.0 / 4294967296.0));
        dinv[i] = rsqrtf(sum);   // sum >= 1 always
    }
    s[tid] = v;
    __syncthreads();
    #pragma unroll
    for (int off = 128; off > 0; off >>= 1) {
        if (tid < off) s[tid] += s[tid + off];
        __syncthreads();
    }
    if (tid == 0) bsum[blockIdx.x] = s[0];
}

__global__ __launch_bounds__(512) void scan2_kernel(int* __restrict__ bsum, int nb) {
    __shared__ int s[512];
    int tid = threadIdx.x;
    int v = (tid < nb) ? bsum[tid] : 0;
    s[tid] = v;
    __syncthreads();
    #pragma unroll
    for (int off = 1; off < 512; off <<= 1) {
        int t = s[tid];
        int u = (tid >= off) ? s[tid - off] : 0;
        __syncthreads();
        s[tid] = t + u;
        __syncthreads();
    }
    if (tid < nb) bsum[tid] = (tid == 0) ? 0 : s[tid - 1];
}

__global__ __launch_bounds__(256) void scan3_kernel(const int* __restrict__ cnt,
                                                    const int* __restrict__ bsum,
                                                    int* __restrict__ rowptr, int n) {
    __shared__ int s[256];
    int tid = threadIdx.x;
    int i = blockIdx.x * 256 + tid;
    int v = (i < n) ? cnt[i] : 0;
    s[tid] = v;
    __syncthreads();
    #pragma unroll
    for (int off = 1; off < 256; off <<= 1) {
        int t = s[tid];
        int u = (tid >= off) ? s[tid - off] : 0;
        __syncthreads();
        s[tid] = t + u;
        __syncthreads();
    }
    if (i < n) rowptr[i] = bsum[blockIdx.x] + s[tid] - v;
    if (i == 0) rowptr[n] = N_EDGES;
}

// interleaved edge record: low dword = src, high dword = norm bits
__global__ void place_kernel(const int* __restrict__ src, const int* __restrict__ dst,
                             const float* __restrict__ w, const float* __restrict__ dinv,
                             const int* __restrict__ rowptr, const int* __restrict__ rank,
                             unsigned long long* __restrict__ edges, int E) {
    int e = blockIdx.x * blockDim.x + threadIdx.x;
    if (e < E) {
        int s = src[e], d = dst[e];
        int pos = rowptr[d] + rank[e];
        float nrm = dinv[s] * w[e] * dinv[d];
        unsigned long long rec = ((unsigned long long)__float_as_uint(nrm) << 32)
                               | (unsigned int)s;
        edges[pos] = rec;
    }
}

// ---------------- GEMM: H = X @ W  (f32 compute, bf16 store; X f32 or bf16) ----------------

template<bool XBF16>
__global__ __launch_bounds__(256) void gemm_kernel(const void* __restrict__ Xin,
                                                   const float* __restrict__ W,
                                                   unsigned short* __restrict__ Hout,
                                                   int M, int FOUT, int HSTRIDE) {
    __shared__ float sX[64 * 128];
    __shared__ float sW[128 * 64];
    int row0 = blockIdx.x * 64;
    int col0 = blockIdx.y * 64;
    int tid = threadIdx.x;

    for (int i = tid; i < 128 * 16; i += 256) {
        int k = i >> 4, c4 = i & 15;
        int j = col0 + c4 * 4;
        float4 v = make_float4(0.f, 0.f, 0.f, 0.f);
        if (j + 3 < FOUT) v = *(const float4*)&W[k * FOUT + j];
        ((float4*)sW)[i] = v;
    }
    if (XBF16) {
        const unsigned int* X = (const unsigned int*)Xin;   // 64 dwords per row
        for (int i = tid; i < 64 * 64; i += 256) {
            int r = i >> 6, c2 = i & 63;
            int row = row0 + r;
            unsigned int u = (row < M) ? X[(size_t)row * 64 + c2] : 0u;
            sX[r * 128 + 2 * c2]     = bflo(u);
            sX[r * 128 + 2 * c2 + 1] = bfhi(u);
        }
    } else {
        const float* X = (const float*)Xin;
        for (int i = tid; i < 64 * 32; i += 256) {
            int r = i >> 5;
            int row = row0 + r;
            float4 v = make_float4(0.f, 0.f, 0.f, 0.f);
            if (row < M) v = *(const float4*)&X[(size_t)row * 128 + (i & 31) * 4];
            ((float4*)sX)[i] = v;
        }
    }
    __syncthreads();

    int tx = tid & 15, ty = tid >> 4;
    float acc[4][4] = {};
    const float* xb = &sX[(ty * 4) * 128];
    #pragma unroll 4
    for (int k = 0; k < 128; k++) {
        float4 wv = ((const float4*)sW)[(k << 4) + tx];
        float x0 = xb[k];
        float x1 = xb[128 + k];
        float x2 = xb[256 + k];
        float x3 = xb[384 + k];
        acc[0][0] += x0 * wv.x; acc[0][1] += x0 * wv.y; acc[0][2] += x0 * wv.z; acc[0][3] += x0 * wv.w;
        acc[1][0] += x1 * wv.x; acc[1][1] += x1 * wv.y; acc[1][2] += x1 * wv.z; acc[1][3] += x1 * wv.w;
        acc[2][0] += x2 * wv.x; acc[2][1] += x2 * wv.y; acc[2][2] += x2 * wv.z; acc[2][3] += x2 * wv.w;
        acc[3][0] += x3 * wv.x; acc[3][1] += x3 * wv.y; acc[3][2] += x3 * wv.z; acc[3][3] += x3 * wv.w;
    }

    #pragma unroll
    for (int i2 = 0; i2 < 4; i2++) {
        int row = row0 + ty * 4 + i2;
        if (row < M) {
            int j = col0 + tx * 4;
            if (j + 3 < FOUT) {
                *(ushort4*)&Hout[(size_t)row * HSTRIDE + j] =
                    make_ushort4(f2bf(acc[i2][0]), f2bf(acc[i2][1]),
                                 f2bf(acc[i2][2]), f2bf(acc[i2][3]));
            }
        }
    }
}

// ---------------- Aggregation F=128 (bf16 H, bf16 out): one wave/node ----------------

template<bool RELU>
__global__ __launch_bounds__(256) void gather128bf_kernel(
        const unsigned int* __restrict__ H,                 // N x 64 dwords (bf16x2)
        const int* __restrict__ rowptr,
        const unsigned long long* __restrict__ edges,       // (src, normbits)
        const float* __restrict__ dinv, const float* __restrict__ bias,
        unsigned int* __restrict__ out, int n) {            // N x 64 dwords (bf16x2)
    int wave = threadIdx.x >> 6;
    int lane = threadIdx.x & 63;
    int node = blockIdx.x * 4 + wave;
    if (node >= n) return;
    // wave-uniform bounds -> scalar loads for edge records
    int beg = __builtin_amdgcn_readfirstlane(rowptr[node]);
    int end = __builtin_amdgcn_readfirstlane(rowptr[node + 1]);
    float ax = 0.f, ay = 0.f;
    int e = beg;
    for (; e + 7 < end; e += 8) {
        int s[8]; float w[8]; unsigned int u[8];
        #pragma unroll
        for (int i = 0; i < 8; i++) {
            unsigned long long rec = edges[e + i];
            s[i] = (int)(unsigned int)rec;
            w[i] = __uint_as_float((unsigned int)(rec >> 32));
        }
        #pragma unroll
        for (int i = 0; i < 8; i++) { u[i] = H[(size_t)s[i] * 64 + lane]; }
        #pragma unroll
        for (int i = 0; i < 8; i++) {
            ax += w[i] * bflo(u[i]);
            ay += w[i] * bfhi(u[i]);
        }
    }
    for (; e < end; e++) {
        unsigned long long rec = edges[e];
        float w0 = __uint_as_float((unsigned int)(rec >> 32));
        unsigned int u = H[(size_t)(unsigned int)rec * 64 + lane];
        ax += w0 * bflo(u);
        ay += w0 * bfhi(u);
    }
    float di = dinv[node];
    float sw = di * di;
    unsigned int us = H[(size_t)node * 64 + lane];
    ax += sw * bflo(us);
    ay += sw * bfhi(us);
    float2 bv = ((const float2*)bias)[lane];
    ax += bv.x; ay += bv.y;
    if (RELU) { ax = fmaxf(ax, 0.f); ay = fmaxf(ay, 0.f); }
    unsigned int pk = (unsigned int)f2bf(ax) | ((unsigned int)f2bf(ay) << 16);
    out[(size_t)node * 64 + lane] = pk;
}

// F=40 (bf16 H padded to 32 dwords/row): one wave/node, lanes 0..19, f32 out
__global__ __launch_bounds__(256) void gather40bf_kernel(
        const unsigned int* __restrict__ H,   // N x 32 dwords (20 used)
        const int* __restrict__ rowptr,
        const unsigned long long* __restrict__ edges,
        const float* __restrict__ dinv, const float* __restrict__ bias,
        float* __restrict__ out, int n) {
    int wave = threadIdx.x >> 6;
    int lane = threadIdx.x & 63;
    int node = blockIdx.x * 4 + wave;
    if (node >= n) return;
    int beg = __builtin_amdgcn_readfirstlane(rowptr[node]);
    int end = __builtin_amdgcn_readfirstlane(rowptr[node + 1]);
    if (lane >= 20) return;
    float ax = 0.f, ay = 0.f;
    int e = beg;
    for (; e + 3 < end; e += 4) {
        unsigned long long r0 = edges[e];
        unsigned long long r1 = edges[e + 1];
        unsigned long long r2 = edges[e + 2];
        unsigned long long r3 = edges[e + 3];
        unsigned int u0 = H[(size_t)(unsigned int)r0 * 32 + lane];
        unsigned int u1 = H[(size_t)(unsigned int)r1 * 32 + lane];
        unsigned int u2 = H[(size_t)(unsigned int)r2 * 32 + lane];
        unsigned int u3 = H[(size_t)(unsigned int)r3 * 32 + lane];
        float w0 = __uint_as_float((unsigned int)(r0 >> 32));
        float w1 = __uint_as_float((unsigned int)(r1 >> 32));
        float w2 = __uint_as_float((unsigned int)(r2 >> 32));
        float w3 = __uint_as_float((unsigned int)(r3 >> 32));
        ax += w0 * bflo(u0); ay += w0 * bfhi(u0);
        ax += w1 * bflo(u1); ay += w1 * bfhi(u1);
        ax += w2 * bflo(u2); ay += w2 * bfhi(u2);
        ax += w3 * bflo(u3); ay += w3 * bfhi(u3);
    }
    for (; e < end; e++) {
        unsigned long long rec = edges[e];
        float w0 = __uint_as_float((unsigned int)(rec >> 32));
        unsigned int u = H[(size_t)(unsigned int)rec * 32 + lane];
        ax += w0 * bflo(u); ay += w0 * bfhi(u);
    }
    float di = dinv[node];
    float sw = di * di;
    unsigned int us = H[(size_t)node * 32 + lane];
    ax += sw * bflo(us); ay += sw * bfhi(us);
    float2 bv = ((const float2*)bias)[lane];
    ax += bv.x; ay += bv.y;
    *(float2*)&out[(size_t)node * 40 + 2 * lane] = make_float2(ax, ay);
}

// ---------------- launch ----------------

extern "C" void kernel_launch(void* const* d_in, const int* in_sizes, int n_in,
                              void* d_out, int out_size, void* d_ws, size_t ws_size,
                              hipStream_t stream) {
    const float* x  = (const float*)d_in[0];
    const int*   ei = (const int*)d_in[1];
    const float* ew = (const float*)d_in[2];
    const float* W1 = (const float*)d_in[3];
    const float* b1 = (const float*)d_in[4];
    const float* W2 = (const float*)d_in[5];
    const float* b2 = (const float*)d_in[6];
    const float* W3 = (const float*)d_in[7];
    const float* b3 = (const float*)d_in[8];
    float* out = (float*)d_out;

    const int N = N_NODES, E = N_EDGES;
    const int* src = ei;
    const int* dst = ei + E;

    char* p = (char*)d_ws;
    unsigned long long* packed = (unsigned long long*)p; p += 800000;   // N u64
    float* dinv   = (float*)p; p += 400000;
    int*   cnt    = (int*)p;   p += 400000;
    int*   rowptr = (int*)p;   p += 400016;
    int*   bsum   = (int*)p;   p += 2048;
    int*   rank   = (int*)p;   p += 6400000;                            // E i32
    unsigned long long* edges = (unsigned long long*)p; p += 12800000;  // E u64
    void*  A      = (void*)p;  p += (size_t)N * 128 * 2;                // bf16 H
    void*  B      = (void*)p;                                           // bf16 layer output

    int nb = (N + 255) / 256;
    int eb = (E + 255) / 256;

    init_packed_kernel<<<nb, 256, 0, stream>>>(packed, N);
    edge_pass1_kernel<<<eb, 256, 0, stream>>>(dst, ew, packed, rank, E);
    scan1_kernel<<<SCAN_NB, 256, 0, stream>>>(packed, cnt, dinv, bsum, N);
    scan2_kernel<<<1, 512, 0, stream>>>(bsum, SCAN_NB);
    scan3_kernel<<<SCAN_NB, 256, 0, stream>>>(cnt, bsum, rowptr, N);
    place_kernel<<<eb, 256, 0, stream>>>(src, dst, ew, dinv, rowptr, rank, edges, E);

    int rt = (N + 63) / 64;
    dim3 g128(rt, 2);
    dim3 g40(rt, 1);
    int gb = (N + 3) / 4;

    // layer 1: A(bf16) = x(f32)@W1 ; B(bf16) = relu(agg(A)+self+b1)
    gemm_kernel<false><<<g128, 256, 0, stream>>>(x, W1, (unsigned short*)A, N, 128, 128);
    gather128bf_kernel<true><<<gb, 256, 0, stream>>>((const unsigned int*)A, rowptr, edges, dinv, b1, (unsigned int*)B, N);
    // layer 2: bf16 input
    gemm_kernel<true><<<g128, 256, 0, stream>>>(B, W2, (unsigned short*)A, N, 128, 128);
    gather128bf_kernel<true><<<gb, 256, 0, stream>>>((const unsigned int*)A, rowptr, edges, dinv, b2, (unsigned int*)B, N);
    // layer 3: H3 bf16 padded to 64-short rows; f32 output
    gemm_kernel<true><<<g40, 256, 0, stream>>>(B, W3, (unsigned short*)A, N, 40, 64);
    gather40bf_kernel<<<gb, 256, 0, stream>>>((const unsigned int*)A, rowptr, edges, dinv, b3, out, N);
}

// Round 8
// 516.822 us; speedup vs baseline: 1.4620x; 1.2293x over previous
//
#include <hip/hip_runtime.h>

#define N_NODES 100000
#define N_EDGES 1600000
#define SCAN_NB ((N_NODES + 255) / 256)   // 391

// packed degree: bits 63..52 = count, bits 51..0 = sum(w) in 2^-32 fixed point
#define CNT_SHIFT 52
#define WSUM_MASK ((1ULL << 52) - 1)

typedef __attribute__((ext_vector_type(8))) short short8;   // MFMA A/B frag (8 bf16)
typedef __attribute__((ext_vector_type(4))) float f32x4;    // MFMA C/D frag

__device__ inline unsigned short f2bf(float f) {   // round-to-nearest-even
    unsigned int u = __float_as_uint(f);
    u += 0x7FFFu + ((u >> 16) & 1u);
    return (unsigned short)(u >> 16);
}
__device__ inline float bflo(unsigned int u) { return __uint_as_float(u << 16); }
__device__ inline float bfhi(unsigned int u) { return __uint_as_float(u & 0xFFFF0000u); }
__device__ inline float bf2f(unsigned short h) { return __uint_as_float((unsigned int)h << 16); }

// ---------------- CSR build ----------------

__global__ void init_packed_kernel(unsigned long long* __restrict__ packed, int n) {
    int i = blockIdx.x * blockDim.x + threadIdx.x;
    if (i < n) packed[i] = 1ULL << 32;   // self-loop weight 1.0, count 0
}

__global__ void edge_pass1_kernel(const int* __restrict__ dst, const float* __restrict__ w,
                                  unsigned long long* __restrict__ packed,
                                  int* __restrict__ rank, int E) {
    int e = blockIdx.x * blockDim.x + threadIdx.x;
    if (e < E) {
        int d = dst[e];
        unsigned long long inc = (1ULL << CNT_SHIFT)
                               + (unsigned long long)((double)w[e] * 4294967296.0);
        unsigned long long old = atomicAdd(&packed[d], inc);
        rank[e] = (int)(old >> CNT_SHIFT);
    }
}

// scan1 fused with extract: packed -> cnt, dinv, block sums
__global__ __launch_bounds__(256) void scan1_kernel(const unsigned long long* __restrict__ packed,
                                                    int* __restrict__ cnt, float* __restrict__ dinv,
                                                    int* __restrict__ bsum, int n) {
    __shared__ int s[256];
    int tid = threadIdx.x;
    int i = blockIdx.x * 256 + tid;
    int v = 0;
    if (i < n) {
        unsigned long long pk = packed[i];
        v = (int)(pk >> CNT_SHIFT);
        cnt[i] = v;
        float sum = (float)((double)(pk & WSUM_MASK) * (1.0 / 4294967296.0));
        dinv[i] = rsqrtf(sum);   // sum >= 1 always
    }
    s[tid] = v;
    __syncthreads();
    #pragma unroll
    for (int off = 128; off > 0; off >>= 1) {
        if (tid < off) s[tid] += s[tid + off];
        __syncthreads();
    }
    if (tid == 0) bsum[blockIdx.x] = s[0];
}

__global__ __launch_bounds__(512) void scan2_kernel(int* __restrict__ bsum, int nb) {
    __shared__ int s[512];
    int tid = threadIdx.x;
    int v = (tid < nb) ? bsum[tid] : 0;
    s[tid] = v;
    __syncthreads();
    #pragma unroll
    for (int off = 1; off < 512; off <<= 1) {
        int t = s[tid];
        int u = (tid >= off) ? s[tid - off] : 0;
        __syncthreads();
        s[tid] = t + u;
        __syncthreads();
    }
    if (tid < nb) bsum[tid] = (tid == 0) ? 0 : s[tid - 1];
}

__global__ __launch_bounds__(256) void scan3_kernel(const int* __restrict__ cnt,
                                                    const int* __restrict__ bsum,
                                                    int* __restrict__ rowptr, int n) {
    __shared__ int s[256];
    int tid = threadIdx.x;
    int i = blockIdx.x * 256 + tid;
    int v = (i < n) ? cnt[i] : 0;
    s[tid] = v;
    __syncthreads();
    #pragma unroll
    for (int off = 1; off < 256; off <<= 1) {
        int t = s[tid];
        int u = (tid >= off) ? s[tid - off] : 0;
        __syncthreads();
        s[tid] = t + u;
        __syncthreads();
    }
    if (i < n) rowptr[i] = bsum[blockIdx.x] + s[tid] - v;
    if (i == 0) rowptr[n] = N_EDGES;
}

// interleaved edge record: low dword = src, high dword = norm bits
__global__ void place_kernel(const int* __restrict__ src, const int* __restrict__ dst,
                             const float* __restrict__ w, const float* __restrict__ dinv,
                             const int* __restrict__ rowptr, const int* __restrict__ rank,
                             unsigned long long* __restrict__ edges, int E) {
    int e = blockIdx.x * blockDim.x + threadIdx.x;
    if (e < E) {
        int s = src[e], d = dst[e];
        int pos = rowptr[d] + rank[e];
        float nrm = dinv[s] * w[e] * dinv[d];
        unsigned long long rec = ((unsigned long long)__float_as_uint(nrm) << 32)
                               | (unsigned int)s;
        edges[pos] = rec;
    }
}

// ---------------- MFMA GEMM: H(bf16) = A @ W,  K=128 fixed ----------------
// Block: 128 rows x FOUT cols, 256 threads (4 waves x 32 rows).
// A-fragments loaded straight from global (16B/lane). W split hi/lo bf16 into LDS,
// transposed n-major, stride 136 shorts (16B-aligned frags, uniform 8-way b128).
// AF32: A is f32 -> in-register split, 3rd pass Alo@Whi recovers f32 accuracy.

#define BSTR 136

template<int NCT, int FOUT, int HSTRIDE, bool AF32>
__global__ __launch_bounds__(256) void gemm_mfma_kernel(
        const void* __restrict__ Ain, const float* __restrict__ W,
        unsigned short* __restrict__ Hout, int M) {
    __shared__ unsigned short sBhi[NCT * 16 * BSTR];
    __shared__ unsigned short sBlo[NCT * 16 * BSTR];
    int tid = threadIdx.x;

    if (FOUT != NCT * 16) {   // zero-pad unused B columns
        unsigned int* z0 = (unsigned int*)sBhi;
        unsigned int* z1 = (unsigned int*)sBlo;
        for (int i = tid; i < NCT * 16 * BSTR / 2; i += 256) { z0[i] = 0u; z1[i] = 0u; }
        __syncthreads();
    }
    // stage W (K=128 x FOUT, row-major) -> split bf16, transposed [n][k]
    for (int i = tid; i < 128 * FOUT; i += 256) {
        int k = i / FOUT, n = i - k * FOUT;
        float v = W[i];
        unsigned short hi = f2bf(v);
        unsigned short lo = f2bf(v - bf2f(hi));
        sBhi[n * BSTR + k] = hi;
        sBlo[n * BSTR + k] = lo;
    }
    __syncthreads();

    int lane = tid & 63;
    int m16 = lane & 15;
    int q = lane >> 4;
    int wv = tid >> 6;
    int wbase = blockIdx.x * 128 + wv * 32;

    // A fragments: 2 row-tiles x 4 k-steps, from global
    short8 afr[2][4];
    short8 alo[2][4];
    #pragma unroll
    for (int mt = 0; mt < 2; mt++) {
        int row = wbase + mt * 16 + m16;
        row = (row < M) ? row : (M - 1);   // clamp: no OOB fault, stores guarded
        if (AF32) {
            const float* ar = (const float*)Ain + (size_t)row * 128;
            #pragma unroll
            for (int kt = 0; kt < 4; kt++) {
                const float* p = ar + kt * 32 + q * 8;
                float4 a = *(const float4*)p;
                float4 b = *(const float4*)(p + 4);
                float vv[8] = {a.x, a.y, a.z, a.w, b.x, b.y, b.z, b.w};
                short8 h, l;
                #pragma unroll
                for (int j = 0; j < 8; j++) {
                    unsigned short hb = f2bf(vv[j]);
                    h[j] = (short)hb;
                    l[j] = (short)f2bf(vv[j] - bf2f(hb));
                }
                afr[mt][kt] = h;
                alo[mt][kt] = l;
            }
        } else {
            const unsigned short* ar = (const unsigned short*)Ain + (size_t)row * 128;
            #pragma unroll
            for (int kt = 0; kt < 4; kt++) {
                afr[mt][kt] = *(const short8*)(ar + kt * 32 + q * 8);
            }
        }
    }

    f32x4 acc[2][NCT] = {};
    #pragma unroll
    for (int kt = 0; kt < 4; kt++) {
        #pragma unroll
        for (int ct = 0; ct < NCT; ct++) {
            const unsigned short* bp = &sBhi[(ct * 16 + m16) * BSTR + kt * 32 + q * 8];
            short8 bh = *(const short8*)bp;
            short8 bl = *(const short8*)(bp + (NCT * 16 * BSTR));  // sBlo is contiguous after sBhi? not guaranteed — use direct
            bl = *(const short8*)&sBlo[(ct * 16 + m16) * BSTR + kt * 32 + q * 8];
            #pragma unroll
            for (int mt = 0; mt < 2; mt++) {
                acc[mt][ct] = __builtin_amdgcn_mfma_f32_16x16x32_bf16(afr[mt][kt], bh, acc[mt][ct], 0, 0, 0);
                acc[mt][ct] = __builtin_amdgcn_mfma_f32_16x16x32_bf16(afr[mt][kt], bl, acc[mt][ct], 0, 0, 0);
                if (AF32)
                    acc[mt][ct] = __builtin_amdgcn_mfma_f32_16x16x32_bf16(alo[mt][kt], bh, acc[mt][ct], 0, 0, 0);
            }
        }
    }

    // epilogue: C/D layout col=lane&15, row=(lane>>4)*4+reg
    #pragma unroll
    for (int mt = 0; mt < 2; mt++) {
        #pragma unroll
        for (int ct = 0; ct < NCT; ct++) {
            int col = ct * 16 + m16;
            if (FOUT != NCT * 16 && col >= FOUT) continue;
            #pragma unroll
            for (int r = 0; r < 4; r++) {
                int row = wbase + mt * 16 + q * 4 + r;
                if (row < M)
                    Hout[(size_t)row * HSTRIDE + col] = f2bf(acc[mt][ct][r]);
            }
        }
    }
}

// ---------------- Aggregation F=128 (bf16 H, bf16 out): one wave/node ----------------

template<bool RELU>
__global__ __launch_bounds__(256) void gather128bf_kernel(
        const unsigned int* __restrict__ H,                 // N x 64 dwords (bf16x2)
        const int* __restrict__ rowptr,
        const unsigned long long* __restrict__ edges,       // (src, normbits)
        const float* __restrict__ dinv, const float* __restrict__ bias,
        unsigned int* __restrict__ out, int n) {            // N x 64 dwords (bf16x2)
    int wave = threadIdx.x >> 6;
    int lane = threadIdx.x & 63;
    int node = blockIdx.x * 4 + wave;
    if (node >= n) return;
    int beg = __builtin_amdgcn_readfirstlane(rowptr[node]);
    int end = __builtin_amdgcn_readfirstlane(rowptr[node + 1]);
    float ax = 0.f, ay = 0.f;
    int e = beg;
    for (; e + 7 < end; e += 8) {
        int s[8]; float w[8]; unsigned int u[8];
        #pragma unroll
        for (int i = 0; i < 8; i++) {
            unsigned long long rec = edges[e + i];
            s[i] = (int)(unsigned int)rec;
            w[i] = __uint_as_float((unsigned int)(rec >> 32));
        }
        #pragma unroll
        for (int i = 0; i < 8; i++) { u[i] = H[(size_t)s[i] * 64 + lane]; }
        #pragma unroll
        for (int i = 0; i < 8; i++) {
            ax += w[i] * bflo(u[i]);
            ay += w[i] * bfhi(u[i]);
        }
    }
    for (; e < end; e++) {
        unsigned long long rec = edges[e];
        float w0 = __uint_as_float((unsigned int)(rec >> 32));
        unsigned int u = H[(size_t)(unsigned int)rec * 64 + lane];
        ax += w0 * bflo(u);
        ay += w0 * bfhi(u);
    }
    float di = dinv[node];
    float sw = di * di;
    unsigned int us = H[(size_t)node * 64 + lane];
    ax += sw * bflo(us);
    ay += sw * bfhi(us);
    float2 bv = ((const float2*)bias)[lane];
    ax += bv.x; ay += bv.y;
    if (RELU) { ax = fmaxf(ax, 0.f); ay = fmaxf(ay, 0.f); }
    unsigned int pk = (unsigned int)f2bf(ax) | ((unsigned int)f2bf(ay) << 16);
    out[(size_t)node * 64 + lane] = pk;
}

// F=40 (bf16 H padded to 32 dwords/row): one wave/node, lanes 0..19, f32 out
__global__ __launch_bounds__(256) void gather40bf_kernel(
        const unsigned int* __restrict__ H,   // N x 32 dwords (20 used)
        const int* __restrict__ rowptr,
        const unsigned long long* __restrict__ edges,
        const float* __restrict__ dinv, const float* __restrict__ bias,
        float* __restrict__ out, int n) {
    int wave = threadIdx.x >> 6;
    int lane = threadIdx.x & 63;
    int node = blockIdx.x * 4 + wave;
    if (node >= n) return;
    int beg = __builtin_amdgcn_readfirstlane(rowptr[node]);
    int end = __builtin_amdgcn_readfirstlane(rowptr[node + 1]);
    if (lane >= 20) return;
    float ax = 0.f, ay = 0.f;
    int e = beg;
    for (; e + 3 < end; e += 4) {
        unsigned long long r0 = edges[e];
        unsigned long long r1 = edges[e + 1];
        unsigned long long r2 = edges[e + 2];
        unsigned long long r3 = edges[e + 3];
        unsigned int u0 = H[(size_t)(unsigned int)r0 * 32 + lane];
        unsigned int u1 = H[(size_t)(unsigned int)r1 * 32 + lane];
        unsigned int u2 = H[(size_t)(unsigned int)r2 * 32 + lane];
        unsigned int u3 = H[(size_t)(unsigned int)r3 * 32 + lane];
        float w0 = __uint_as_float((unsigned int)(r0 >> 32));
        float w1 = __uint_as_float((unsigned int)(r1 >> 32));
        float w2 = __uint_as_float((unsigned int)(r2 >> 32));
        float w3 = __uint_as_float((unsigned int)(r3 >> 32));
        ax += w0 * bflo(u0); ay += w0 * bfhi(u0);
        ax += w1 * bflo(u1); ay += w1 * bfhi(u1);
        ax += w2 * bflo(u2); ay += w2 * bfhi(u2);
        ax += w3 * bflo(u3); ay += w3 * bfhi(u3);
    }
    for (; e < end; e++) {
        unsigned long long rec = edges[e];
        float w0 = __uint_as_float((unsigned int)(rec >> 32));
        unsigned int u = H[(size_t)(unsigned int)rec * 32 + lane];
        ax += w0 * bflo(u); ay += w0 * bfhi(u);
    }
    float di = dinv[node];
    float sw = di * di;
    unsigned int us = H[(size_t)node * 32 + lane];
    ax += sw * bflo(us); ay += sw * bfhi(us);
    float2 bv = ((const float2*)bias)[lane];
    ax += bv.x; ay += bv.y;
    *(float2*)&out[(size_t)node * 40 + 2 * lane] = make_float2(ax, ay);
}

// ---------------- launch ----------------

extern "C" void kernel_launch(void* const* d_in, const int* in_sizes, int n_in,
                              void* d_out, int out_size, void* d_ws, size_t ws_size,
                              hipStream_t stream) {
    const float* x  = (const float*)d_in[0];
    const int*   ei = (const int*)d_in[1];
    const float* ew = (const float*)d_in[2];
    const float* W1 = (const float*)d_in[3];
    const float* b1 = (const float*)d_in[4];
    const float* W2 = (const float*)d_in[5];
    const float* b2 = (const float*)d_in[6];
    const float* W3 = (const float*)d_in[7];
    const float* b3 = (const float*)d_in[8];
    float* out = (float*)d_out;

    const int N = N_NODES, E = N_EDGES;
    const int* src = ei;
    const int* dst = ei + E;

    char* p = (char*)d_ws;
    unsigned long long* packed = (unsigned long long*)p; p += 800000;   // N u64
    float* dinv   = (float*)p; p += 400000;
    int*   cnt    = (int*)p;   p += 400000;
    int*   rowptr = (int*)p;   p += 400016;
    int*   bsum   = (int*)p;   p += 2048;
    int*   rank   = (int*)p;   p += 6400000;                            // E i32
    unsigned long long* edges = (unsigned long long*)p; p += 12800000;  // E u64
    void*  A      = (void*)p;  p += (size_t)N * 128 * 2;                // bf16 H
    void*  B      = (void*)p;                                           // bf16 layer output

    int nb = (N + 255) / 256;
    int eb = (E + 255) / 256;

    init_packed_kernel<<<nb, 256, 0, stream>>>(packed, N);
    edge_pass1_kernel<<<eb, 256, 0, stream>>>(dst, ew, packed, rank, E);
    scan1_kernel<<<SCAN_NB, 256, 0, stream>>>(packed, cnt, dinv, bsum, N);
    scan2_kernel<<<1, 512, 0, stream>>>(bsum, SCAN_NB);
    scan3_kernel<<<SCAN_NB, 256, 0, stream>>>(cnt, bsum, rowptr, N);
    place_kernel<<<eb, 256, 0, stream>>>(src, dst, ew, dinv, rowptr, rank, edges, E);

    int gemmb = (N + 127) / 128;   // 782
    int gb = (N + 3) / 4;

    // layer 1: A(bf16) = x(f32)@W1  [3-pass split]
    gemm_mfma_kernel<8, 128, 128, true><<<gemmb, 256, 0, stream>>>(x, W1, (unsigned short*)A, N);
    gather128bf_kernel<true><<<gb, 256, 0, stream>>>((const unsigned int*)A, rowptr, edges, dinv, b1, (unsigned int*)B, N);
    // layer 2: bf16 A, 2-pass W split
    gemm_mfma_kernel<8, 128, 128, false><<<gemmb, 256, 0, stream>>>(B, W2, (unsigned short*)A, N);
    gather128bf_kernel<true><<<gb, 256, 0, stream>>>((const unsigned int*)A, rowptr, edges, dinv, b2, (unsigned int*)B, N);
    // layer 3: FOUT=40 padded to 48 cols, H3 stride 64 shorts
    gemm_mfma_kernel<3, 40, 64, false><<<gemmb, 256, 0, stream>>>(B, W3, (unsigned short*)A, N);
    gather40bf_kernel<<<gb, 256, 0, stream>>>((const unsigned int*)A, rowptr, edges, dinv, b3, out, N);
}